// Round 6
// baseline (1497.188 us; speedup 1.0000x reference)
//
#include <hip/hip_runtime.h>
#include <hip/hip_bf16.h>

// ---------------------------------------------------------------------------
// Mamba2 block on gfx950.  R6: R5 + conv_kernel rewrite (8ch x 16row register
// tile, 16B loads/stores, rolling 4-row window) — was latency-bound at 267us
// with 4B/lane loads and 1 row/thread.
// ---------------------------------------------------------------------------

typedef __bf16 bf16x8 __attribute__((ext_vector_type(8)));
typedef float f32x4 __attribute__((ext_vector_type(4)));
typedef const unsigned int __attribute__((address_space(1)))* gas1_u32;
typedef unsigned int __attribute__((address_space(3)))* las3_u32;

__device__ __forceinline__ float b2f_lo(unsigned u) { union { unsigned i; float f; } x; x.i = u << 16; return x.f; }
__device__ __forceinline__ float b2f_hi(unsigned u) { union { unsigned i; float f; } x; x.i = u & 0xffff0000u; return x.f; }
__device__ __forceinline__ float b2f(unsigned short u) { union { unsigned i; float f; } x; x.i = ((unsigned)u) << 16; return x.f; }
__device__ __forceinline__ unsigned short f2b(float f) {
  union { float f; unsigned i; } x; x.f = f;
  unsigned r = x.i + 0x7fffu + ((x.i >> 16) & 1u);
  return (unsigned short)(r >> 16);
}
__device__ __forceinline__ unsigned pack2(float a, float b) {
  return (unsigned)f2b(a) | ((unsigned)f2b(b) << 16);
}
__device__ __forceinline__ void gll16(const void* g, void* l) {
  __builtin_amdgcn_global_load_lds((gas1_u32)g, (las3_u32)l, 16, 0, 0);
}

// ---------------- weight fp32 -> bf16 (optional zero row-pad) ----------------
__global__ void w2bf(const float* __restrict__ src, unsigned short* __restrict__ dst,
                     long srcN, long totN) {
  const long i = (long)blockIdx.x * 256 + threadIdx.x;
  const long e0 = i << 2;
  if (e0 >= totN) return;
  float4 v = (e0 < srcN) ? ((const float4*)src)[i] : make_float4(0.f, 0.f, 0.f, 0.f);
  uint2 o; o.x = pack2(v.x, v.y); o.y = pack2(v.z, v.w);
  ((uint2*)dst)[i] = o;
}

// ---------------- LayerNorm over 1024, fp32 in -> bf16 out ----------------
__global__ void ln_kernel(const float* __restrict__ x, const float* __restrict__ w,
                          const float* __restrict__ b, unsigned short* __restrict__ out) {
  const int m = blockIdx.x, t = threadIdx.x;
  const float4 v = ((const float4*)(x + (size_t)m * 1024))[t];
  float s = v.x + v.y + v.z + v.w;
  float s2 = v.x * v.x + v.y * v.y + v.z * v.z + v.w * v.w;
  for (int o = 32; o; o >>= 1) { s += __shfl_xor(s, o); s2 += __shfl_xor(s2, o); }
  __shared__ float red[8];
  if ((t & 63) == 0) { red[t >> 6] = s; red[4 + (t >> 6)] = s2; }
  __syncthreads();
  s = red[0] + red[1] + red[2] + red[3];
  s2 = red[4] + red[5] + red[6] + red[7];
  const float mu = s * (1.f / 1024.f);
  const float var = s2 * (1.f / 1024.f) - mu * mu;
  const float rs = rsqrtf(var + 1e-5f);
  const float4 wv = ((const float4*)w)[t];
  const float4 bv = ((const float4*)b)[t];
  uint2 o2;
  o2.x = pack2((v.x - mu) * rs * wv.x + bv.x, (v.y - mu) * rs * wv.y + bv.y);
  o2.y = pack2((v.z - mu) * rs * wv.z + bv.z, (v.w - mu) * rs * wv.w + bv.w);
  ((uint2*)(out + (size_t)m * 1024))[t] = o2;
}

// ---------------- causal depthwise conv(4) + bias + silu ----------------
// Thread = 8 channels x 16 rows.  272 granules x 256 ltiles x 4 b = 1088 blocks.
__global__ __launch_bounds__(256)
void conv_kernel(const unsigned short* __restrict__ xbcr, const float* __restrict__ cw,
                 const float* __restrict__ cb, unsigned short* __restrict__ xs) {
  const int idx = blockIdx.x * 256 + threadIdx.x;
  const int g = idx % 272;          // channel granule (8 ch)
  const int r = idx / 272;
  const int lt = r & 255;           // l-tile (16 rows)
  const int b = r >> 8;
  const int c0 = g << 3;
  const size_t rb = (size_t)b * 4096;
  const unsigned short* src = xbcr + rb * 2176 + c0;
  unsigned short* dst = xs + rb * 2176 + c0;

  float w[8][4], bias[8];
#pragma unroll
  for (int i = 0; i < 8; ++i) {
    const float4 wv = ((const float4*)cw)[c0 + i];
    w[i][0] = wv.x; w[i][1] = wv.y; w[i][2] = wv.z; w[i][3] = wv.w;
    bias[i] = cb[c0 + i];
  }

  float win[4][8];  // rolling window, win[row & 3]
  const int l0 = lt << 4;
#pragma unroll
  for (int k = 0; k < 3; ++k) {
    const int row = l0 - 3 + k;
    float* wr = win[(row + 4) & 3];
    if (row >= 0) {
      const uint4 u = *(const uint4*)(src + (size_t)row * 2176);
      wr[0] = b2f_lo(u.x); wr[1] = b2f_hi(u.x); wr[2] = b2f_lo(u.y); wr[3] = b2f_hi(u.y);
      wr[4] = b2f_lo(u.z); wr[5] = b2f_hi(u.z); wr[6] = b2f_lo(u.w); wr[7] = b2f_hi(u.w);
    } else {
#pragma unroll
      for (int i = 0; i < 8; ++i) wr[i] = 0.f;
    }
  }

  for (int l = l0; l < l0 + 16; ++l) {
    float* wr = win[l & 3];
    {
      const uint4 u = *(const uint4*)(src + (size_t)l * 2176);
      wr[0] = b2f_lo(u.x); wr[1] = b2f_hi(u.x); wr[2] = b2f_lo(u.y); wr[3] = b2f_hi(u.y);
      wr[4] = b2f_lo(u.z); wr[5] = b2f_hi(u.z); wr[6] = b2f_lo(u.w); wr[7] = b2f_hi(u.w);
    }
    float o[8];
#pragma unroll
    for (int i = 0; i < 8; ++i) {
      float a = bias[i];
#pragma unroll
      for (int k = 0; k < 4; ++k) a = fmaf(w[i][k], win[(l - 3 + k + 4) & 3][i], a);
      o[i] = a / (1.f + __expf(-a));
    }
    uint4 ov;
    ov.x = pack2(o[0], o[1]); ov.y = pack2(o[2], o[3]);
    ov.z = pack2(o[4], o[5]); ov.w = pack2(o[6], o[7]);
    *(uint4*)(dst + (size_t)l * 2176) = ov;
  }
}

// ---------------- per-chunk inclusive cumsum of g ----------------
__global__ void cumsum_kernel(const float2* __restrict__ dd, float* __restrict__ cs) {
  const int cidx = blockIdx.x * 4 + (threadIdx.x >> 6);
  const int lane = threadIdx.x & 63;
  const int c = cidx & 63, h = (cidx >> 6) & 31, b = cidx >> 11;
  const size_t row = (size_t)b * 4096 + c * 64 + lane;
  float s = dd[row * 32 + h].x;
#pragma unroll
  for (int off = 1; off < 64; off <<= 1) {
    const float v = __shfl_up(s, off, 64);
    if (lane >= off) s += v;
  }
  cs[(size_t)cidx * 64 + lane] = s;
}

// ---------------- pass A: chunk states S_c (MFMA) ----------------
__global__ __launch_bounds__(256)
void chunk_state(const unsigned short* __restrict__ xs, const float2* __restrict__ dd,
                 const float* __restrict__ cs, unsigned short* __restrict__ SH) {
  const int cidx = blockIdx.x;
  const int c = cidx & 63, h = (cidx >> 6) & 31, b = cidx >> 11;
  const int t = threadIdx.x;
  __shared__ unsigned short At[64][72];  // [p][j] : exp(cs_j-cs63)*dt_j*x_j[p]
  __shared__ unsigned short Bt[64][72];  // [n][j] : B_j[n]
  __shared__ float csL[64], fA[64];
  const size_t rowbase = (size_t)b * 4096 + c * 64;

  if (t < 64) csL[t] = cs[(size_t)cidx * 64 + t];
  __syncthreads();
  if (t < 64) {
    const float dtv = dd[(rowbase + t) * 32 + h].y;
    fA[t] = __expf(csL[t] - csL[63]) * dtv;
  }
  __syncthreads();
#pragma unroll
  for (int cc = 0; cc < 2; ++cc) {
    const int q = t + cc * 256;
    const int j = q >> 3, cb8 = (q & 7) << 3;
    const size_t go = (rowbase + j) * 2176;
    const uint4 xu = *(const uint4*)(xs + go + h * 64 + cb8);
    const float f = fA[j];
    const unsigned short* pu = (const unsigned short*)&xu;
#pragma unroll
    for (int i = 0; i < 8; ++i) At[cb8 + i][j] = f2b(f * b2f(pu[i]));
    const uint4 bu = *(const uint4*)(xs + go + 2048 + cb8);
    const unsigned short* pb = (const unsigned short*)&bu;
#pragma unroll
    for (int i = 0; i < 8; ++i) Bt[cb8 + i][j] = pb[i];
  }
  __syncthreads();

  const int w = t >> 6, lane = t & 63, lr = lane & 15, lk = lane >> 4;
  const int pm = (w & 1) << 5, nm = (w >> 1) << 5;
  f32x4 acc[2][2] = {};
#pragma unroll
  for (int ks = 0; ks < 64; ks += 32) {
    bf16x8 af[2], bfv[2];
#pragma unroll
    for (int ti = 0; ti < 2; ++ti) af[ti] = *(const bf16x8*)&At[pm + ti * 16 + lr][ks + (lk << 3)];
#pragma unroll
    for (int tj = 0; tj < 2; ++tj) bfv[tj] = *(const bf16x8*)&Bt[nm + tj * 16 + lr][ks + (lk << 3)];
#pragma unroll
    for (int ti = 0; ti < 2; ++ti)
#pragma unroll
      for (int tj = 0; tj < 2; ++tj)
        acc[ti][tj] = __builtin_amdgcn_mfma_f32_16x16x32_bf16(af[ti], bfv[tj], acc[ti][tj], 0, 0, 0);
  }
  unsigned short* sp = SH + (size_t)cidx * 4096;
#pragma unroll
  for (int ti = 0; ti < 2; ++ti)
#pragma unroll
    for (int tj = 0; tj < 2; ++tj)
#pragma unroll
      for (int r = 0; r < 4; ++r) {
        const int p = pm + ti * 16 + lk * 4 + r;
        const int n = nm + tj * 16 + lr;
        sp[p * 64 + n] = f2b(acc[ti][tj][r]);
      }
}

// ---------------- pass B: cross-chunk state scan (in-place SH[c] := H0_c) ----------------
__global__ void state_pass(unsigned short* __restrict__ SH, const float* __restrict__ cs) {
  const int bh = blockIdx.x;  // 0..127
  const int t = threadIdx.x;
  float H[16];
#pragma unroll
  for (int i = 0; i < 16; ++i) H[i] = 0.f;
  const size_t base0 = (size_t)bh * 64 * 4096 + t * 16;
  for (int c = 0; c < 64; ++c) {
    const size_t base = base0 + (size_t)c * 4096;
    const uint4 s0 = *(const uint4*)(SH + base);
    const uint4 s1 = *(const uint4*)(SH + base + 8);
    const float wq = __expf(-cs[((size_t)bh * 64 + c) * 64 + 63]);
    uint4 h0, h1;
    h0.x = pack2(H[0], H[1]);  h0.y = pack2(H[2], H[3]);
    h0.z = pack2(H[4], H[5]);  h0.w = pack2(H[6], H[7]);
    h1.x = pack2(H[8], H[9]);  h1.y = pack2(H[10], H[11]);
    h1.z = pack2(H[12], H[13]); h1.w = pack2(H[14], H[15]);
    *(uint4*)(SH + base) = h0;
    *(uint4*)(SH + base + 8) = h1;
    const unsigned short* p0 = (const unsigned short*)&s0;
    const unsigned short* p1 = (const unsigned short*)&s1;
#pragma unroll
    for (int i = 0; i < 8; ++i) H[i] = fmaf(wq, H[i], b2f(p0[i]));
#pragma unroll
    for (int i = 0; i < 8; ++i) H[8 + i] = fmaf(wq, H[8 + i], b2f(p1[i]));
  }
}

// ---------------- pass C: per-chunk y (MFMA) ----------------
__global__ __launch_bounds__(256, 3)
void chunk_y(const unsigned short* __restrict__ xs, const float2* __restrict__ dd,
             const float* __restrict__ cs, const unsigned short* __restrict__ SH,
             const float* __restrict__ Dp, unsigned short* __restrict__ y) {
  const int cidx = blockIdx.x;
  const int c = cidx & 63, h = (cidx >> 6) & 31, b = cidx >> 11;
  const int t = threadIdx.x;
  __shared__ unsigned short Ct[64][72];  // [i][n] C rows (natural)
  __shared__ unsigned short Bt[64][72];  // [j][n] B rows (natural); later sY
  __shared__ unsigned short Mt[64][72];  // [i][j] decay-masked scores
  __shared__ unsigned short Xt[64][72];  // [p][j] dt_j * x_j[p]   (transposed)
  __shared__ unsigned short Ht[64][72];  // [p][n] H0 (natural)
  __shared__ float csL[64], dtL[64];
  const size_t rowbase = (size_t)b * 4096 + c * 64;

  if (t < 64) {
    csL[t] = cs[(size_t)cidx * 64 + t];
    dtL[t] = dd[(rowbase + t) * 32 + h].y;
  }
  __syncthreads();
#pragma unroll
  for (int cc = 0; cc < 2; ++cc) {
    const int q = t + cc * 256;
    const int j = q >> 3, cb8 = (q & 7) << 3;
    const size_t go = (rowbase + j) * 2176;
    const uint4 xu = *(const uint4*)(xs + go + h * 64 + cb8);
    const float f = dtL[j];
    const unsigned short* pu = (const unsigned short*)&xu;
#pragma unroll
    for (int i = 0; i < 8; ++i) Xt[cb8 + i][j] = f2b(f * b2f(pu[i]));
    *(uint4*)&Bt[j][cb8] = *(const uint4*)(xs + go + 2048 + cb8);
    *(uint4*)&Ct[j][cb8] = *(const uint4*)(xs + go + 2112 + cb8);
    // H0 tile: 512 vec8 entries total
    const int p = q >> 3, nb = (q & 7) << 3;
    *(uint4*)&Ht[p][nb] = *(const uint4*)(SH + (size_t)cidx * 4096 + p * 64 + nb);
  }
  __syncthreads();

  const int w = t >> 6, lane = t & 63, lr = lane & 15, lk = lane >> 4;
  // ---- G = C @ B^T (quadrant per wave) ----
  const int im = (w & 1) << 5, jm = (w >> 1) << 5;
  f32x4 G[2][2] = {};
#pragma unroll
  for (int ks = 0; ks < 64; ks += 32) {
    bf16x8 af[2], bfv[2];
#pragma unroll
    for (int ti = 0; ti < 2; ++ti) af[ti] = *(const bf16x8*)&Ct[im + ti * 16 + lr][ks + (lk << 3)];
#pragma unroll
    for (int tj = 0; tj < 2; ++tj) bfv[tj] = *(const bf16x8*)&Bt[jm + tj * 16 + lr][ks + (lk << 3)];
#pragma unroll
    for (int ti = 0; ti < 2; ++ti)
#pragma unroll
      for (int tj = 0; tj < 2; ++tj)
        G[ti][tj] = __builtin_amdgcn_mfma_f32_16x16x32_bf16(af[ti], bfv[tj], G[ti][tj], 0, 0, 0);
  }
  // ---- M[i][j] = (j<=i) exp(cs_j-cs_i) G + (i==j) D/dt ----
  const float Dh = Dp[h];
#pragma unroll
  for (int ti = 0; ti < 2; ++ti)
#pragma unroll
    for (int tj = 0; tj < 2; ++tj)
#pragma unroll
      for (int r = 0; r < 4; ++r) {
        const int i = im + ti * 16 + lk * 4 + r;
        const int j = jm + tj * 16 + lr;
        float mv = 0.f;
        if (j <= i) mv = G[ti][tj][r] * __expf(csL[j] - csL[i]);
        if (j == i) mv += Dh / dtL[i];
        Mt[i][j] = f2b(mv);
      }
  __syncthreads();
  // ---- Y = M @ Xt^T + diag(exp(-cs_i)) (C @ Ht^T) ----
  const int im2 = (w & 1) << 5, pm = (w >> 1) << 5;
  f32x4 Y1[2][2] = {}, Y2[2][2] = {};
#pragma unroll
  for (int ks = 0; ks < 64; ks += 32) {
    bf16x8 am[2], ac[2], bx[2], bh2[2];
#pragma unroll
    for (int ti = 0; ti < 2; ++ti) {
      am[ti] = *(const bf16x8*)&Mt[im2 + ti * 16 + lr][ks + (lk << 3)];
      ac[ti] = *(const bf16x8*)&Ct[im2 + ti * 16 + lr][ks + (lk << 3)];
    }
#pragma unroll
    for (int tj = 0; tj < 2; ++tj) {
      bx[tj] = *(const bf16x8*)&Xt[pm + tj * 16 + lr][ks + (lk << 3)];
      bh2[tj] = *(const bf16x8*)&Ht[pm + tj * 16 + lr][ks + (lk << 3)];
    }
#pragma unroll
    for (int ti = 0; ti < 2; ++ti)
#pragma unroll
      for (int tj = 0; tj < 2; ++tj) {
        Y1[ti][tj] = __builtin_amdgcn_mfma_f32_16x16x32_bf16(am[ti], bx[tj], Y1[ti][tj], 0, 0, 0);
        Y2[ti][tj] = __builtin_amdgcn_mfma_f32_16x16x32_bf16(ac[ti], bh2[tj], Y2[ti][tj], 0, 0, 0);
      }
  }
  // combine, write sY into Bt region (Bt dead after G; all waves past the Mt barrier)
#pragma unroll
  for (int ti = 0; ti < 2; ++ti)
#pragma unroll
    for (int tj = 0; tj < 2; ++tj)
#pragma unroll
      for (int r = 0; r < 4; ++r) {
        const int i = im2 + ti * 16 + lk * 4 + r;
        const int p = pm + tj * 16 + lr;
        const float yv = Y1[ti][tj][r] + __expf(-csL[i]) * Y2[ti][tj][r];
        Bt[i][p] = f2b(yv);
      }
  __syncthreads();
  // coalesced flush
  {
    const int i = t >> 2, p0 = (t & 3) << 4;
    unsigned short* yp = y + (rowbase + i) * 2048 + h * 64 + p0;
    *(uint4*)yp = *(const uint4*)&Bt[i][p0];
    *(uint4*)(yp + 8) = *(const uint4*)&Bt[i][p0 + 8];
  }
}

// ---------------- y *= silu(z); RMSNorm * norm_w (in place, bf16) ----------------
__global__ void gate_rms(unsigned short* __restrict__ y, const unsigned short* __restrict__ zb,
                         const float* __restrict__ nw) {
  const int m = blockIdx.x, t = threadIdx.x;
  unsigned short* yp = y + (size_t)m * 2048 + (t << 3);
  const unsigned short* zp = zb + (size_t)m * 2048 + (t << 3);
  const uint4 yu = *(const uint4*)yp;
  const uint4 zu = *(const uint4*)zp;
  float g[8];
  {
    const unsigned yw[4] = {yu.x, yu.y, yu.z, yu.w};
    const unsigned zw[4] = {zu.x, zu.y, zu.z, zu.w};
#pragma unroll
    for (int i = 0; i < 4; ++i) {
      const float z0 = b2f_lo(zw[i]), z1 = b2f_hi(zw[i]);
      g[2 * i] = b2f_lo(yw[i]) * (z0 / (1.f + expf(-z0)));
      g[2 * i + 1] = b2f_hi(yw[i]) * (z1 / (1.f + expf(-z1)));
    }
  }
  float ss = 0.f;
#pragma unroll
  for (int j = 0; j < 8; ++j) ss += g[j] * g[j];
  for (int o = 32; o; o >>= 1) ss += __shfl_xor(ss, o);
  __shared__ float red[4];
  if ((t & 63) == 0) red[t >> 6] = ss;
  __syncthreads();
  ss = red[0] + red[1] + red[2] + red[3];
  const float sc = rsqrtf(ss * (1.f / 2048.f) + 1e-5f);
  const float4 w0 = ((const float4*)nw)[t * 2];
  const float4 w1 = ((const float4*)nw)[t * 2 + 1];
  uint4 o4;
  o4.x = pack2(g[0] * sc * w0.x, g[1] * sc * w0.y);
  o4.y = pack2(g[2] * sc * w0.z, g[3] * sc * w0.w);
  o4.z = pack2(g[4] * sc * w1.x, g[5] * sc * w1.y);
  o4.w = pack2(g[6] * sc * w1.z, g[7] * sc * w1.w);
  *(uint4*)yp = o4;
}

// ---------------- bf16 A*B^T MFMA GEMM, 128x128 tile, BK=32 (m97 structure) ----------------
// EPI 1: Cf = resid + acc
// EPI 2: Cb = bf16(gelu(acc + bias[col]))
// EPI 3: Cf = resid + acc + bias[col]
// EPI 4: split zxbcdt: col<2048 -> Cb2 (z); col<4224 -> Cb (xBC);
//        col<4256 -> (g,dt) -> ((float2*)Cf); bias=dt_bias, resid=A_log
template <int EPI>
__global__ __launch_bounds__(256, 3)
void gemm_bt(const unsigned short* __restrict__ A, const unsigned short* __restrict__ B,
             float* __restrict__ Cf, unsigned short* __restrict__ Cb,
             unsigned short* __restrict__ Cb2,
             const float* __restrict__ bias, const float* __restrict__ resid,
             int K, int ldc) {
  __shared__ unsigned short As[128][32];
  __shared__ unsigned short Bs[128][32];
  const int tid = threadIdx.x;
  const size_t m0 = (size_t)blockIdx.y * 128;
  const size_t n0 = (size_t)blockIdx.x * 128;
  const int wave = tid >> 6, lane = tid & 63;
  const int wm = (wave & 1) << 6, wn = (wave >> 1) << 6;
  const int lr = lane & 15, lk = lane >> 4;

  f32x4 acc[4][4] = {};

  const int r1 = tid >> 2;
  const int c1 = (tid & 3) << 3;
  const unsigned short* ga0 = A + (m0 + r1) * (size_t)K + c1;
  const unsigned short* ga1 = ga0 + (size_t)64 * K;
  const unsigned short* gb0 = B + (n0 + r1) * (size_t)K + c1;
  const unsigned short* gb1 = gb0 + (size_t)64 * K;
  unsigned short* la0 = &As[0][0] + (tid << 3);
  unsigned short* la1 = la0 + 2048;
  unsigned short* lb0 = &Bs[0][0] + (tid << 3);
  unsigned short* lb1 = lb0 + 2048;

  for (int k0 = 0; k0 < K; k0 += 32) {
    __syncthreads();
    gll16(ga0 + k0, la0);
    gll16(ga1 + k0, la1);
    gll16(gb0 + k0, lb0);
    gll16(gb1 + k0, lb1);
    __syncthreads();
    bf16x8 af[4], bfr[4];
#pragma unroll
    for (int i = 0; i < 4; ++i) af[i] = *(const bf16x8*)&As[wm + i * 16 + lr][lk << 3];
#pragma unroll
    for (int j = 0; j < 4; ++j) bfr[j] = *(const bf16x8*)&Bs[wn + j * 16 + lr][lk << 3];
#pragma unroll
    for (int i = 0; i < 4; ++i)
#pragma unroll
      for (int j = 0; j < 4; ++j)
        acc[i][j] = __builtin_amdgcn_mfma_f32_16x16x32_bf16(af[i], bfr[j], acc[i][j], 0, 0, 0);
  }

#pragma unroll
  for (int i = 0; i < 4; ++i) {
    const size_t rbase = m0 + wm + i * 16 + lk * 4;
#pragma unroll
    for (int j = 0; j < 4; ++j) {
      const int col = (int)n0 + wn + j * 16 + lr;
#pragma unroll
      for (int r = 0; r < 4; ++r) {
        const float v = acc[i][j][r];
        const size_t row = rbase + r;
        if (EPI == 1) {
          const size_t idx = row * (size_t)ldc + col;
          Cf[idx] = resid[idx] + v;
        } else if (EPI == 2) {
          const size_t idx = row * (size_t)ldc + col;
          const float tt = v + bias[col];
          Cb[idx] = f2b(0.5f * tt * (1.f + erff(tt * 0.70710678118654752f)));
        } else if (EPI == 3) {
          const size_t idx = row * (size_t)ldc + col;
          Cf[idx] = resid[idx] + v + bias[col];
        } else {  // EPI 4
          if (col < 2048) {
            Cb2[row * 2048 + col] = f2b(v);
          } else if (col < 4224) {
            Cb[row * 2176 + (col - 2048)] = f2b(v);
          } else if (col < 4256) {
            const int hh = col - 4224;
            const float raw = v + bias[hh];
            const float dt = (raw > 20.f) ? raw : log1pf(expf(raw));
            const float g = expf(resid[hh]) * dt;
            ((float2*)Cf)[row * 32 + hh] = make_float2(g, dt);
          }
        }
      }
    }
  }
}

// ---------------------------------------------------------------------------
extern "C" void kernel_launch(void* const* d_in, const int* in_sizes, int n_in,
                              void* d_out, int out_size, void* d_ws, size_t ws_size,
                              hipStream_t stream) {
  const float* x = (const float*)d_in[0];
  const float* ln1w = (const float*)d_in[1];
  const float* ln1b = (const float*)d_in[2];
  const float* ln2w = (const float*)d_in[3];
  const float* ln2b = (const float*)d_in[4];
  const float* ipw = (const float*)d_in[5];
  const float* cw = (const float*)d_in[6];
  const float* cb = (const float*)d_in[7];
  const float* dtb = (const float*)d_in[8];
  const float* alog = (const float*)d_in[9];
  const float* Dp = (const float*)d_in[10];
  const float* nw = (const float*)d_in[11];
  const float* opw = (const float*)d_in[12];
  const float* fcw = (const float*)d_in[13];
  const float* fcb = (const float*)d_in[14];
  const float* pjw = (const float*)d_in[15];
  const float* pjb = (const float*)d_in[16];
  float* out = (float*)d_out;

  char* ws = (char*)d_ws;
  size_t off = 0;
  auto alloc = [&](size_t bytes) {
    char* p = ws + off;
    off += (bytes + 255) & ~(size_t)255;
    return p;
  };
  unsigned short* wip = (unsigned short*)alloc(4352ull * 1024 * 2);   // 8.9 MB
  unsigned short* wop = (unsigned short*)alloc(1024ull * 2048 * 2);   // 4.2 MB
  unsigned short* wfc = (unsigned short*)alloc(4096ull * 1024 * 2);   // 8.4 MB
  unsigned short* wpj = (unsigned short*)alloc(1024ull * 4096 * 2);   // 8.4 MB
  unsigned short* xbcr = (unsigned short*)alloc(16384ull * 2176 * 2); // 71 MB; SH + hm alias
  unsigned short* xs = (unsigned short*)alloc(16384ull * 2176 * 2);   // 71 MB
  float2* dd = (float2*)alloc(16384ull * 32 * 8);                     // 4.2 MB (g, dt)
  unsigned short* yb = (unsigned short*)alloc(16384ull * 2048 * 2);   // 67 MB; front = xn
  float* cs = (float*)alloc(8192ull * 64 * 4);                        // 2 MB per-chunk cumsum
  // aliases (lifetimes disjoint):
  unsigned short* xn = yb;                    // LN out — dead before chunk_y writes yb
  unsigned short* SH = xbcr;                  // chunk states/H0 (67 MB) — xbcr dead post-conv
  unsigned short* hm = xbcr;                  // MLP hidden 128 MB over xbcr+xs (both dead)
  unsigned short* zb = (unsigned short*)out;  // z (bf16) in d_out — dead before gemm1

  // weights -> bf16
  w2bf<<<4352, 256, 0, stream>>>(ipw, wip, 4358144L, 4456448L);
  w2bf<<<2048, 256, 0, stream>>>(opw, wop, 2097152L, 2097152L);
  w2bf<<<4096, 256, 0, stream>>>(fcw, wfc, 4194304L, 4194304L);
  w2bf<<<4096, 256, 0, stream>>>(pjw, wpj, 4194304L, 4194304L);

  // mamba2 branch
  ln_kernel<<<16384, 256, 0, stream>>>(x, ln1w, ln1b, xn);
  gemm_bt<4><<<dim3(34, 128), 256, 0, stream>>>(xn, wip, (float*)dd, xbcr, zb, dtb, alog, 1024, 0);
  conv_kernel<<<1088, 256, 0, stream>>>(xbcr, cw, cb, xs);
  cumsum_kernel<<<2048, 256, 0, stream>>>(dd, cs);
  chunk_state<<<8192, 256, 0, stream>>>(xs, dd, cs, SH);
  state_pass<<<128, 256, 0, stream>>>(SH, cs);
  chunk_y<<<8192, 256, 0, stream>>>(xs, dd, cs, SH, Dp, yb);
  gate_rms<<<16384, 256, 0, stream>>>(yb, zb, nw);
  gemm_bt<1><<<dim3(8, 128), 256, 0, stream>>>(yb, wop, out, nullptr, nullptr, nullptr, x, 2048, 1024);

  // mlp branch
  ln_kernel<<<16384, 256, 0, stream>>>(out, ln2w, ln2b, xn);
  gemm_bt<2><<<dim3(32, 128), 256, 0, stream>>>(xn, wfc, nullptr, hm, nullptr, fcb, nullptr, 1024, 4096);
  gemm_bt<3><<<dim3(8, 128), 256, 0, stream>>>(hm, wpj, out, nullptr, nullptr, pjb, out, 4096, 1024);
}

// Round 7
// 1134.841 us; speedup vs baseline: 1.3193x; 1.3193x over previous
//
#include <hip/hip_runtime.h>
#include <hip/hip_bf16.h>

// ---------------------------------------------------------------------------
// Mamba2 block on gfx950.  R7: R6 + conv fix — full unroll with STATIC register
// array indexing (R6's dynamic win[l&3] demoted arrays to scratch: VGPR=52,
// VALUBusy=86%, 440us).  8ch x 8row tile, rcp-based silu, 2176 blocks.
// ---------------------------------------------------------------------------

typedef __bf16 bf16x8 __attribute__((ext_vector_type(8)));
typedef float f32x4 __attribute__((ext_vector_type(4)));
typedef const unsigned int __attribute__((address_space(1)))* gas1_u32;
typedef unsigned int __attribute__((address_space(3)))* las3_u32;

__device__ __forceinline__ float b2f_lo(unsigned u) { union { unsigned i; float f; } x; x.i = u << 16; return x.f; }
__device__ __forceinline__ float b2f_hi(unsigned u) { union { unsigned i; float f; } x; x.i = u & 0xffff0000u; return x.f; }
__device__ __forceinline__ float b2f(unsigned short u) { union { unsigned i; float f; } x; x.i = ((unsigned)u) << 16; return x.f; }
__device__ __forceinline__ unsigned short f2b(float f) {
  union { float f; unsigned i; } x; x.f = f;
  unsigned r = x.i + 0x7fffu + ((x.i >> 16) & 1u);
  return (unsigned short)(r >> 16);
}
__device__ __forceinline__ unsigned pack2(float a, float b) {
  return (unsigned)f2b(a) | ((unsigned)f2b(b) << 16);
}
__device__ __forceinline__ void gll16(const void* g, void* l) {
  __builtin_amdgcn_global_load_lds((gas1_u32)g, (las3_u32)l, 16, 0, 0);
}

// ---------------- weight fp32 -> bf16 (optional zero row-pad) ----------------
__global__ void w2bf(const float* __restrict__ src, unsigned short* __restrict__ dst,
                     long srcN, long totN) {
  const long i = (long)blockIdx.x * 256 + threadIdx.x;
  const long e0 = i << 2;
  if (e0 >= totN) return;
  float4 v = (e0 < srcN) ? ((const float4*)src)[i] : make_float4(0.f, 0.f, 0.f, 0.f);
  uint2 o; o.x = pack2(v.x, v.y); o.y = pack2(v.z, v.w);
  ((uint2*)dst)[i] = o;
}

// ---------------- LayerNorm over 1024, fp32 in -> bf16 out ----------------
__global__ void ln_kernel(const float* __restrict__ x, const float* __restrict__ w,
                          const float* __restrict__ b, unsigned short* __restrict__ out) {
  const int m = blockIdx.x, t = threadIdx.x;
  const float4 v = ((const float4*)(x + (size_t)m * 1024))[t];
  float s = v.x + v.y + v.z + v.w;
  float s2 = v.x * v.x + v.y * v.y + v.z * v.z + v.w * v.w;
  for (int o = 32; o; o >>= 1) { s += __shfl_xor(s, o); s2 += __shfl_xor(s2, o); }
  __shared__ float red[8];
  if ((t & 63) == 0) { red[t >> 6] = s; red[4 + (t >> 6)] = s2; }
  __syncthreads();
  s = red[0] + red[1] + red[2] + red[3];
  s2 = red[4] + red[5] + red[6] + red[7];
  const float mu = s * (1.f / 1024.f);
  const float var = s2 * (1.f / 1024.f) - mu * mu;
  const float rs = rsqrtf(var + 1e-5f);
  const float4 wv = ((const float4*)w)[t];
  const float4 bv = ((const float4*)b)[t];
  uint2 o2;
  o2.x = pack2((v.x - mu) * rs * wv.x + bv.x, (v.y - mu) * rs * wv.y + bv.y);
  o2.y = pack2((v.z - mu) * rs * wv.z + bv.z, (v.w - mu) * rs * wv.w + bv.w);
  ((uint2*)(out + (size_t)m * 1024))[t] = o2;
}

// ---------------- causal depthwise conv(4) + bias + silu ----------------
// Thread = 8 channels x 8 rows; all register-array indices compile-time.
// 272 granules x 512 ltiles x 4 b = 2176 blocks.
__global__ __launch_bounds__(256)
void conv_kernel(const unsigned short* __restrict__ xbcr, const float* __restrict__ cw,
                 const float* __restrict__ cb, unsigned short* __restrict__ xs) {
  const int idx = blockIdx.x * 256 + threadIdx.x;
  const int g = idx % 272;          // channel granule (8 ch)
  const int r = idx / 272;
  const int lt = r & 511;           // l-tile (8 rows)
  const int b = r >> 9;
  const int c0 = g << 3;
  const size_t rb = (size_t)b * 4096;
  const unsigned short* src = xbcr + rb * 2176 + c0;
  unsigned short* dst = xs + rb * 2176 + c0;

  float w[8][4], bias[8];
#pragma unroll
  for (int i = 0; i < 8; ++i) {
    const float4 wv = ((const float4*)cw)[c0 + i];
    w[i][0] = wv.x; w[i][1] = wv.y; w[i][2] = wv.z; w[i][3] = wv.w;
    bias[i] = cb[c0 + i];
  }

  const int l0 = lt << 3;           // multiple of 8 -> l0 & 3 == 0
  float win[4][8];                  // win[row & 3][ch] — all indices static
  // preload rows l0-3 .. l0-1 into win[(s+1)&3]
#pragma unroll
  for (int s = 0; s < 3; ++s) {
    float* wr = win[(s + 1) & 3];
    const int row = l0 - 3 + s;
    if (row >= 0) {
      const uint4 u = *(const uint4*)(src + (size_t)row * 2176);
      wr[0] = b2f_lo(u.x); wr[1] = b2f_hi(u.x); wr[2] = b2f_lo(u.y); wr[3] = b2f_hi(u.y);
      wr[4] = b2f_lo(u.z); wr[5] = b2f_hi(u.z); wr[6] = b2f_lo(u.w); wr[7] = b2f_hi(u.w);
    } else {
#pragma unroll
      for (int i = 0; i < 8; ++i) wr[i] = 0.f;
    }
  }

#pragma unroll
  for (int s = 0; s < 8; ++s) {
    const int l = l0 + s;
    float* wr = win[s & 3];         // (l0+s)&3 == s&3, static
    {
      const uint4 u = *(const uint4*)(src + (size_t)l * 2176);
      wr[0] = b2f_lo(u.x); wr[1] = b2f_hi(u.x); wr[2] = b2f_lo(u.y); wr[3] = b2f_hi(u.y);
      wr[4] = b2f_lo(u.z); wr[5] = b2f_hi(u.z); wr[6] = b2f_lo(u.w); wr[7] = b2f_hi(u.w);
    }
    float o[8];
#pragma unroll
    for (int i = 0; i < 8; ++i) {
      float a = bias[i];
#pragma unroll
      for (int k = 0; k < 4; ++k) a = fmaf(w[i][k], win[(s + 1 + k) & 3][i], a);
      o[i] = a * __builtin_amdgcn_rcpf(1.f + __expf(-a));
    }
    uint4 ov;
    ov.x = pack2(o[0], o[1]); ov.y = pack2(o[2], o[3]);
    ov.z = pack2(o[4], o[5]); ov.w = pack2(o[6], o[7]);
    *(uint4*)(dst + (size_t)l * 2176) = ov;
  }
}

// ---------------- per-chunk inclusive cumsum of g ----------------
__global__ void cumsum_kernel(const float2* __restrict__ dd, float* __restrict__ cs) {
  const int cidx = blockIdx.x * 4 + (threadIdx.x >> 6);
  const int lane = threadIdx.x & 63;
  const int c = cidx & 63, h = (cidx >> 6) & 31, b = cidx >> 11;
  const size_t row = (size_t)b * 4096 + c * 64 + lane;
  float s = dd[row * 32 + h].x;
#pragma unroll
  for (int off = 1; off < 64; off <<= 1) {
    const float v = __shfl_up(s, off, 64);
    if (lane >= off) s += v;
  }
  cs[(size_t)cidx * 64 + lane] = s;
}

// ---------------- pass A: chunk states S_c (MFMA) ----------------
__global__ __launch_bounds__(256)
void chunk_state(const unsigned short* __restrict__ xs, const float2* __restrict__ dd,
                 const float* __restrict__ cs, unsigned short* __restrict__ SH) {
  const int cidx = blockIdx.x;
  const int c = cidx & 63, h = (cidx >> 6) & 31, b = cidx >> 11;
  const int t = threadIdx.x;
  __shared__ unsigned short At[64][72];  // [p][j] : exp(cs_j-cs63)*dt_j*x_j[p]
  __shared__ unsigned short Bt[64][72];  // [n][j] : B_j[n]
  __shared__ float csL[64], fA[64];
  const size_t rowbase = (size_t)b * 4096 + c * 64;

  if (t < 64) csL[t] = cs[(size_t)cidx * 64 + t];
  __syncthreads();
  if (t < 64) {
    const float dtv = dd[(rowbase + t) * 32 + h].y;
    fA[t] = __expf(csL[t] - csL[63]) * dtv;
  }
  __syncthreads();
#pragma unroll
  for (int cc = 0; cc < 2; ++cc) {
    const int q = t + cc * 256;
    const int j = q >> 3, cb8 = (q & 7) << 3;
    const size_t go = (rowbase + j) * 2176;
    const uint4 xu = *(const uint4*)(xs + go + h * 64 + cb8);
    const float f = fA[j];
    const unsigned short* pu = (const unsigned short*)&xu;
#pragma unroll
    for (int i = 0; i < 8; ++i) At[cb8 + i][j] = f2b(f * b2f(pu[i]));
    const uint4 bu = *(const uint4*)(xs + go + 2048 + cb8);
    const unsigned short* pb = (const unsigned short*)&bu;
#pragma unroll
    for (int i = 0; i < 8; ++i) Bt[cb8 + i][j] = pb[i];
  }
  __syncthreads();

  const int w = t >> 6, lane = t & 63, lr = lane & 15, lk = lane >> 4;
  const int pm = (w & 1) << 5, nm = (w >> 1) << 5;
  f32x4 acc[2][2] = {};
#pragma unroll
  for (int ks = 0; ks < 64; ks += 32) {
    bf16x8 af[2], bfv[2];
#pragma unroll
    for (int ti = 0; ti < 2; ++ti) af[ti] = *(const bf16x8*)&At[pm + ti * 16 + lr][ks + (lk << 3)];
#pragma unroll
    for (int tj = 0; tj < 2; ++tj) bfv[tj] = *(const bf16x8*)&Bt[nm + tj * 16 + lr][ks + (lk << 3)];
#pragma unroll
    for (int ti = 0; ti < 2; ++ti)
#pragma unroll
      for (int tj = 0; tj < 2; ++tj)
        acc[ti][tj] = __builtin_amdgcn_mfma_f32_16x16x32_bf16(af[ti], bfv[tj], acc[ti][tj], 0, 0, 0);
  }
  unsigned short* sp = SH + (size_t)cidx * 4096;
#pragma unroll
  for (int ti = 0; ti < 2; ++ti)
#pragma unroll
    for (int tj = 0; tj < 2; ++tj)
#pragma unroll
      for (int r = 0; r < 4; ++r) {
        const int p = pm + ti * 16 + lk * 4 + r;
        const int n = nm + tj * 16 + lr;
        sp[p * 64 + n] = f2b(acc[ti][tj][r]);
      }
}

// ---------------- pass B: cross-chunk state scan (in-place SH[c] := H0_c) ----------------
__global__ void state_pass(unsigned short* __restrict__ SH, const float* __restrict__ cs) {
  const int bh = blockIdx.x;  // 0..127
  const int t = threadIdx.x;
  float H[16];
#pragma unroll
  for (int i = 0; i < 16; ++i) H[i] = 0.f;
  const size_t base0 = (size_t)bh * 64 * 4096 + t * 16;
  for (int c = 0; c < 64; ++c) {
    const size_t base = base0 + (size_t)c * 4096;
    const uint4 s0 = *(const uint4*)(SH + base);
    const uint4 s1 = *(const uint4*)(SH + base + 8);
    const float wq = __expf(-cs[((size_t)bh * 64 + c) * 64 + 63]);
    uint4 h0, h1;
    h0.x = pack2(H[0], H[1]);  h0.y = pack2(H[2], H[3]);
    h0.z = pack2(H[4], H[5]);  h0.w = pack2(H[6], H[7]);
    h1.x = pack2(H[8], H[9]);  h1.y = pack2(H[10], H[11]);
    h1.z = pack2(H[12], H[13]); h1.w = pack2(H[14], H[15]);
    *(uint4*)(SH + base) = h0;
    *(uint4*)(SH + base + 8) = h1;
    const unsigned short* p0 = (const unsigned short*)&s0;
    const unsigned short* p1 = (const unsigned short*)&s1;
#pragma unroll
    for (int i = 0; i < 8; ++i) H[i] = fmaf(wq, H[i], b2f(p0[i]));
#pragma unroll
    for (int i = 0; i < 8; ++i) H[8 + i] = fmaf(wq, H[8 + i], b2f(p1[i]));
  }
}

// ---------------- pass C: per-chunk y (MFMA) ----------------
__global__ __launch_bounds__(256, 3)
void chunk_y(const unsigned short* __restrict__ xs, const float2* __restrict__ dd,
             const float* __restrict__ cs, const unsigned short* __restrict__ SH,
             const float* __restrict__ Dp, unsigned short* __restrict__ y) {
  const int cidx = blockIdx.x;
  const int c = cidx & 63, h = (cidx >> 6) & 31, b = cidx >> 11;
  const int t = threadIdx.x;
  __shared__ unsigned short Ct[64][72];  // [i][n] C rows (natural)
  __shared__ unsigned short Bt[64][72];  // [j][n] B rows (natural); later sY
  __shared__ unsigned short Mt[64][72];  // [i][j] decay-masked scores
  __shared__ unsigned short Xt[64][72];  // [p][j] dt_j * x_j[p]   (transposed)
  __shared__ unsigned short Ht[64][72];  // [p][n] H0 (natural)
  __shared__ float csL[64], dtL[64];
  const size_t rowbase = (size_t)b * 4096 + c * 64;

  if (t < 64) {
    csL[t] = cs[(size_t)cidx * 64 + t];
    dtL[t] = dd[(rowbase + t) * 32 + h].y;
  }
  __syncthreads();
#pragma unroll
  for (int cc = 0; cc < 2; ++cc) {
    const int q = t + cc * 256;
    const int j = q >> 3, cb8 = (q & 7) << 3;
    const size_t go = (rowbase + j) * 2176;
    const uint4 xu = *(const uint4*)(xs + go + h * 64 + cb8);
    const float f = dtL[j];
    const unsigned short* pu = (const unsigned short*)&xu;
#pragma unroll
    for (int i = 0; i < 8; ++i) Xt[cb8 + i][j] = f2b(f * b2f(pu[i]));
    *(uint4*)&Bt[j][cb8] = *(const uint4*)(xs + go + 2048 + cb8);
    *(uint4*)&Ct[j][cb8] = *(const uint4*)(xs + go + 2112 + cb8);
    // H0 tile: 512 vec8 entries total
    const int p = q >> 3, nb = (q & 7) << 3;
    *(uint4*)&Ht[p][nb] = *(const uint4*)(SH + (size_t)cidx * 4096 + p * 64 + nb);
  }
  __syncthreads();

  const int w = t >> 6, lane = t & 63, lr = lane & 15, lk = lane >> 4;
  // ---- G = C @ B^T (quadrant per wave) ----
  const int im = (w & 1) << 5, jm = (w >> 1) << 5;
  f32x4 G[2][2] = {};
#pragma unroll
  for (int ks = 0; ks < 64; ks += 32) {
    bf16x8 af[2], bfv[2];
#pragma unroll
    for (int ti = 0; ti < 2; ++ti) af[ti] = *(const bf16x8*)&Ct[im + ti * 16 + lr][ks + (lk << 3)];
#pragma unroll
    for (int tj = 0; tj < 2; ++tj) bfv[tj] = *(const bf16x8*)&Bt[jm + tj * 16 + lr][ks + (lk << 3)];
#pragma unroll
    for (int ti = 0; ti < 2; ++ti)
#pragma unroll
      for (int tj = 0; tj < 2; ++tj)
        G[ti][tj] = __builtin_amdgcn_mfma_f32_16x16x32_bf16(af[ti], bfv[tj], G[ti][tj], 0, 0, 0);
  }
  // ---- M[i][j] = (j<=i) exp(cs_j-cs_i) G + (i==j) D/dt ----
  const float Dh = Dp[h];
#pragma unroll
  for (int ti = 0; ti < 2; ++ti)
#pragma unroll
    for (int tj = 0; tj < 2; ++tj)
#pragma unroll
      for (int r = 0; r < 4; ++r) {
        const int i = im + ti * 16 + lk * 4 + r;
        const int j = jm + tj * 16 + lr;
        float mv = 0.f;
        if (j <= i) mv = G[ti][tj][r] * __expf(csL[j] - csL[i]);
        if (j == i) mv += Dh / dtL[i];
        Mt[i][j] = f2b(mv);
      }
  __syncthreads();
  // ---- Y = M @ Xt^T + diag(exp(-cs_i)) (C @ Ht^T) ----
  const int im2 = (w & 1) << 5, pm = (w >> 1) << 5;
  f32x4 Y1[2][2] = {}, Y2[2][2] = {};
#pragma unroll
  for (int ks = 0; ks < 64; ks += 32) {
    bf16x8 am[2], ac[2], bx[2], bh2[2];
#pragma unroll
    for (int ti = 0; ti < 2; ++ti) {
      am[ti] = *(const bf16x8*)&Mt[im2 + ti * 16 + lr][ks + (lk << 3)];
      ac[ti] = *(const bf16x8*)&Ct[im2 + ti * 16 + lr][ks + (lk << 3)];
    }
#pragma unroll
    for (int tj = 0; tj < 2; ++tj) {
      bx[tj] = *(const bf16x8*)&Xt[pm + tj * 16 + lr][ks + (lk << 3)];
      bh2[tj] = *(const bf16x8*)&Ht[pm + tj * 16 + lr][ks + (lk << 3)];
    }
#pragma unroll
    for (int ti = 0; ti < 2; ++ti)
#pragma unroll
      for (int tj = 0; tj < 2; ++tj) {
        Y1[ti][tj] = __builtin_amdgcn_mfma_f32_16x16x32_bf16(am[ti], bx[tj], Y1[ti][tj], 0, 0, 0);
        Y2[ti][tj] = __builtin_amdgcn_mfma_f32_16x16x32_bf16(ac[ti], bh2[tj], Y2[ti][tj], 0, 0, 0);
      }
  }
  // combine, write sY into Bt region (Bt dead after G; all waves past the Mt barrier)
#pragma unroll
  for (int ti = 0; ti < 2; ++ti)
#pragma unroll
    for (int tj = 0; tj < 2; ++tj)
#pragma unroll
      for (int r = 0; r < 4; ++r) {
        const int i = im2 + ti * 16 + lk * 4 + r;
        const int p = pm + tj * 16 + lr;
        const float yv = Y1[ti][tj][r] + __expf(-csL[i]) * Y2[ti][tj][r];
        Bt[i][p] = f2b(yv);
      }
  __syncthreads();
  // coalesced flush
  {
    const int i = t >> 2, p0 = (t & 3) << 4;
    unsigned short* yp = y + (rowbase + i) * 2048 + h * 64 + p0;
    *(uint4*)yp = *(const uint4*)&Bt[i][p0];
    *(uint4*)(yp + 8) = *(const uint4*)&Bt[i][p0 + 8];
  }
}

// ---------------- y *= silu(z); RMSNorm * norm_w (in place, bf16) ----------------
__global__ void gate_rms(unsigned short* __restrict__ y, const unsigned short* __restrict__ zb,
                         const float* __restrict__ nw) {
  const int m = blockIdx.x, t = threadIdx.x;
  unsigned short* yp = y + (size_t)m * 2048 + (t << 3);
  const unsigned short* zp = zb + (size_t)m * 2048 + (t << 3);
  const uint4 yu = *(const uint4*)yp;
  const uint4 zu = *(const uint4*)zp;
  float g[8];
  {
    const unsigned yw[4] = {yu.x, yu.y, yu.z, yu.w};
    const unsigned zw[4] = {zu.x, zu.y, zu.z, zu.w};
#pragma unroll
    for (int i = 0; i < 4; ++i) {
      const float z0 = b2f_lo(zw[i]), z1 = b2f_hi(zw[i]);
      g[2 * i] = b2f_lo(yw[i]) * (z0 / (1.f + expf(-z0)));
      g[2 * i + 1] = b2f_hi(yw[i]) * (z1 / (1.f + expf(-z1)));
    }
  }
  float ss = 0.f;
#pragma unroll
  for (int j = 0; j < 8; ++j) ss += g[j] * g[j];
  for (int o = 32; o; o >>= 1) ss += __shfl_xor(ss, o);
  __shared__ float red[4];
  if ((t & 63) == 0) red[t >> 6] = ss;
  __syncthreads();
  ss = red[0] + red[1] + red[2] + red[3];
  const float sc = rsqrtf(ss * (1.f / 2048.f) + 1e-5f);
  const float4 w0 = ((const float4*)nw)[t * 2];
  const float4 w1 = ((const float4*)nw)[t * 2 + 1];
  uint4 o4;
  o4.x = pack2(g[0] * sc * w0.x, g[1] * sc * w0.y);
  o4.y = pack2(g[2] * sc * w0.z, g[3] * sc * w0.w);
  o4.z = pack2(g[4] * sc * w1.x, g[5] * sc * w1.y);
  o4.w = pack2(g[6] * sc * w1.z, g[7] * sc * w1.w);
  *(uint4*)yp = o4;
}

// ---------------- bf16 A*B^T MFMA GEMM, 128x128 tile, BK=32 (m97 structure) ----------------
// EPI 1: Cf = resid + acc
// EPI 2: Cb = bf16(gelu(acc + bias[col]))
// EPI 3: Cf = resid + acc + bias[col]
// EPI 4: split zxbcdt: col<2048 -> Cb2 (z); col<4224 -> Cb (xBC);
//        col<4256 -> (g,dt) -> ((float2*)Cf); bias=dt_bias, resid=A_log
template <int EPI>
__global__ __launch_bounds__(256, 3)
void gemm_bt(const unsigned short* __restrict__ A, const unsigned short* __restrict__ B,
             float* __restrict__ Cf, unsigned short* __restrict__ Cb,
             unsigned short* __restrict__ Cb2,
             const float* __restrict__ bias, const float* __restrict__ resid,
             int K, int ldc) {
  __shared__ unsigned short As[128][32];
  __shared__ unsigned short Bs[128][32];
  const int tid = threadIdx.x;
  const size_t m0 = (size_t)blockIdx.y * 128;
  const size_t n0 = (size_t)blockIdx.x * 128;
  const int wave = tid >> 6, lane = tid & 63;
  const int wm = (wave & 1) << 6, wn = (wave >> 1) << 6;
  const int lr = lane & 15, lk = lane >> 4;

  f32x4 acc[4][4] = {};

  const int r1 = tid >> 2;
  const int c1 = (tid & 3) << 3;
  const unsigned short* ga0 = A + (m0 + r1) * (size_t)K + c1;
  const unsigned short* ga1 = ga0 + (size_t)64 * K;
  const unsigned short* gb0 = B + (n0 + r1) * (size_t)K + c1;
  const unsigned short* gb1 = gb0 + (size_t)64 * K;
  unsigned short* la0 = &As[0][0] + (tid << 3);
  unsigned short* la1 = la0 + 2048;
  unsigned short* lb0 = &Bs[0][0] + (tid << 3);
  unsigned short* lb1 = lb0 + 2048;

  for (int k0 = 0; k0 < K; k0 += 32) {
    __syncthreads();
    gll16(ga0 + k0, la0);
    gll16(ga1 + k0, la1);
    gll16(gb0 + k0, lb0);
    gll16(gb1 + k0, lb1);
    __syncthreads();
    bf16x8 af[4], bfr[4];
#pragma unroll
    for (int i = 0; i < 4; ++i) af[i] = *(const bf16x8*)&As[wm + i * 16 + lr][lk << 3];
#pragma unroll
    for (int j = 0; j < 4; ++j) bfr[j] = *(const bf16x8*)&Bs[wn + j * 16 + lr][lk << 3];
#pragma unroll
    for (int i = 0; i < 4; ++i)
#pragma unroll
      for (int j = 0; j < 4; ++j)
        acc[i][j] = __builtin_amdgcn_mfma_f32_16x16x32_bf16(af[i], bfr[j], acc[i][j], 0, 0, 0);
  }

#pragma unroll
  for (int i = 0; i < 4; ++i) {
    const size_t rbase = m0 + wm + i * 16 + lk * 4;
#pragma unroll
    for (int j = 0; j < 4; ++j) {
      const int col = (int)n0 + wn + j * 16 + lr;
#pragma unroll
      for (int r = 0; r < 4; ++r) {
        const float v = acc[i][j][r];
        const size_t row = rbase + r;
        if (EPI == 1) {
          const size_t idx = row * (size_t)ldc + col;
          Cf[idx] = resid[idx] + v;
        } else if (EPI == 2) {
          const size_t idx = row * (size_t)ldc + col;
          const float tt = v + bias[col];
          Cb[idx] = f2b(0.5f * tt * (1.f + erff(tt * 0.70710678118654752f)));
        } else if (EPI == 3) {
          const size_t idx = row * (size_t)ldc + col;
          Cf[idx] = resid[idx] + v + bias[col];
        } else {  // EPI 4
          if (col < 2048) {
            Cb2[row * 2048 + col] = f2b(v);
          } else if (col < 4224) {
            Cb[row * 2176 + (col - 2048)] = f2b(v);
          } else if (col < 4256) {
            const int hh = col - 4224;
            const float raw = v + bias[hh];
            const float dt = (raw > 20.f) ? raw : log1pf(expf(raw));
            const float g = expf(resid[hh]) * dt;
            ((float2*)Cf)[row * 32 + hh] = make_float2(g, dt);
          }
        }
      }
    }
  }
}

// ---------------------------------------------------------------------------
extern "C" void kernel_launch(void* const* d_in, const int* in_sizes, int n_in,
                              void* d_out, int out_size, void* d_ws, size_t ws_size,
                              hipStream_t stream) {
  const float* x = (const float*)d_in[0];
  const float* ln1w = (const float*)d_in[1];
  const float* ln1b = (const float*)d_in[2];
  const float* ln2w = (const float*)d_in[3];
  const float* ln2b = (const float*)d_in[4];
  const float* ipw = (const float*)d_in[5];
  const float* cw = (const float*)d_in[6];
  const float* cb = (const float*)d_in[7];
  const float* dtb = (const float*)d_in[8];
  const float* alog = (const float*)d_in[9];
  const float* Dp = (const float*)d_in[10];
  const float* nw = (const float*)d_in[11];
  const float* opw = (const float*)d_in[12];
  const float* fcw = (const float*)d_in[13];
  const float* fcb = (const float*)d_in[14];
  const float* pjw = (const float*)d_in[15];
  const float* pjb = (const float*)d_in[16];
  float* out = (float*)d_out;

  char* ws = (char*)d_ws;
  size_t off = 0;
  auto alloc = [&](size_t bytes) {
    char* p = ws + off;
    off += (bytes + 255) & ~(size_t)255;
    return p;
  };
  unsigned short* wip = (unsigned short*)alloc(4352ull * 1024 * 2);   // 8.9 MB
  unsigned short* wop = (unsigned short*)alloc(1024ull * 2048 * 2);   // 4.2 MB
  unsigned short* wfc = (unsigned short*)alloc(4096ull * 1024 * 2);   // 8.4 MB
  unsigned short* wpj = (unsigned short*)alloc(1024ull * 4096 * 2);   // 8.4 MB
  unsigned short* xbcr = (unsigned short*)alloc(16384ull * 2176 * 2); // 71 MB; SH + hm alias
  unsigned short* xs = (unsigned short*)alloc(16384ull * 2176 * 2);   // 71 MB
  float2* dd = (float2*)alloc(16384ull * 32 * 8);                     // 4.2 MB (g, dt)
  unsigned short* yb = (unsigned short*)alloc(16384ull * 2048 * 2);   // 67 MB; front = xn
  float* cs = (float*)alloc(8192ull * 64 * 4);                        // 2 MB per-chunk cumsum
  // aliases (lifetimes disjoint):
  unsigned short* xn = yb;                    // LN out — dead before chunk_y writes yb
  unsigned short* SH = xbcr;                  // chunk states/H0 (67 MB) — xbcr dead post-conv
  unsigned short* hm = xbcr;                  // MLP hidden 128 MB over xbcr+xs (both dead)
  unsigned short* zb = (unsigned short*)out;  // z (bf16) in d_out — dead before gemm1

  // weights -> bf16
  w2bf<<<4352, 256, 0, stream>>>(ipw, wip, 4358144L, 4456448L);
  w2bf<<<2048, 256, 0, stream>>>(opw, wop, 2097152L, 2097152L);
  w2bf<<<4096, 256, 0, stream>>>(fcw, wfc, 4194304L, 4194304L);
  w2bf<<<4096, 256, 0, stream>>>(pjw, wpj, 4194304L, 4194304L);

  // mamba2 branch
  ln_kernel<<<16384, 256, 0, stream>>>(x, ln1w, ln1b, xn);
  gemm_bt<4><<<dim3(34, 128), 256, 0, stream>>>(xn, wip, (float*)dd, xbcr, zb, dtb, alog, 1024, 0);
  conv_kernel<<<2176, 256, 0, stream>>>(xbcr, cw, cb, xs);
  cumsum_kernel<<<2048, 256, 0, stream>>>(dd, cs);
  chunk_state<<<8192, 256, 0, stream>>>(xs, dd, cs, SH);
  state_pass<<<128, 256, 0, stream>>>(SH, cs);
  chunk_y<<<8192, 256, 0, stream>>>(xs, dd, cs, SH, Dp, yb);
  gate_rms<<<16384, 256, 0, stream>>>(yb, zb, nw);
  gemm_bt<1><<<dim3(8, 128), 256, 0, stream>>>(yb, wop, out, nullptr, nullptr, nullptr, x, 2048, 1024);

  // mlp branch
  ln_kernel<<<16384, 256, 0, stream>>>(out, ln2w, ln2b, xn);
  gemm_bt<2><<<dim3(32, 128), 256, 0, stream>>>(xn, wfc, nullptr, hm, nullptr, fcb, nullptr, 1024, 4096);
  gemm_bt<3><<<dim3(8, 128), 256, 0, stream>>>(hm, wpj, out, nullptr, nullptr, pjb, out, 4096, 1024);
}